// Round 1
// baseline (698.633 us; speedup 1.0000x reference)
//
#include <hip/hip_runtime.h>
#include <stdint.h>

// MultiHeadedSelfAttention: B=4, C=256, S=4096, O=256, H=4, D=64
// scoresT[t,s] = k_t . q_s  -> standard flash attn with Qfa=K, Kfa=Q, Vfa=V.

#define S_LEN 4096
#define HD 64

typedef __attribute__((ext_vector_type(8))) __bf16 bf16x8;
typedef __attribute__((ext_vector_type(8))) unsigned short u16x8;
typedef __attribute__((ext_vector_type(4))) float f32x4;

__device__ __forceinline__ unsigned short f2bf(float f) {
    unsigned int u = __float_as_uint(f);
    u = (u + 0x7FFFu + ((u >> 16) & 1u)) >> 16;
    return (unsigned short)u;
}

// ---------------- projection: y = W @ X + b  (per batch), K=256 ----------------
// grid 512 = b(4) x ot(8) x st(16); block 256 (one thread = one s, 32 o's)
__global__ __launch_bounds__(256) void proj_kernel(
    const float* __restrict__ X,     // [B,256,4096]
    const float* __restrict__ W,     // [256,256]
    const float* __restrict__ bias,  // [256]
    unsigned short* __restrict__ dst,
    float scale, int transposed)
{
    int tid = threadIdx.x;
    int id  = blockIdx.x;
    int st  = id & 15;
    int ot  = (id >> 4) & 7;
    int b   = id >> 7;
    int o0  = ot * 32;
    int s0  = st * 256;

    const float* Xb = X + ((size_t)b << 20) + s0 + tid;

    float acc[32];
#pragma unroll
    for (int r = 0; r < 32; r++) acc[r] = bias[o0 + r];

    for (int c4 = 0; c4 < 256; c4 += 4) {
        float xv0 = Xb[(size_t)(c4 + 0) << 12];
        float xv1 = Xb[(size_t)(c4 + 1) << 12];
        float xv2 = Xb[(size_t)(c4 + 2) << 12];
        float xv3 = Xb[(size_t)(c4 + 3) << 12];
#pragma unroll
        for (int r = 0; r < 32; r++) {
            // uniform address -> scalar (SGPR) loads
            const float4* wp = (const float4*)(W + (size_t)(o0 + r) * 256 + c4);
            float4 w = *wp;
            acc[r] += w.x * xv0 + w.y * xv1 + w.z * xv2 + w.w * xv3;
        }
    }

    int s = s0 + tid;
    if (transposed) {
        // dst[(b*4+h)][s][d0..d0+31]  (bf16), h = o0>>6, d0 = o0&63
        unsigned short tmp[32];
#pragma unroll
        for (int r = 0; r < 32; r++) tmp[r] = f2bf(acc[r] * scale);
        int h = o0 >> 6, d0 = o0 & 63;
        unsigned short* dp = dst + ((size_t)(b * 4 + h) * S_LEN + s) * HD + d0;
#pragma unroll
        for (int u = 0; u < 4; u++) {
            u16x8 v;
#pragma unroll
            for (int i = 0; i < 8; i++) v[i] = tmp[u * 8 + i];
            *(u16x8*)(dp + u * 8) = v;
        }
    } else {
        // natural [B*256][4096]
#pragma unroll
        for (int r = 0; r < 32; r++) {
            dst[((size_t)(b * 256 + o0 + r) << 12) + s] = f2bf(acc[r] * scale);
        }
    }
}

// ---------------- flash attention ----------------
// grid 1024 = bh(16) x tblk(64); block 256 (4 waves, wave owns 16 t-rows)
__global__ __launch_bounds__(256) void attn_kernel(
    const unsigned short* __restrict__ Qt,  // [BH][S][64]  (FA "keys", rows = s)
    const unsigned short* __restrict__ Kt,  // [BH][S][64]  (FA "queries", rows = t, pre-scaled 1/8)
    const unsigned short* __restrict__ Vn,  // [B*O][S]
    float* __restrict__ out)                // [B*O][S]
{
    int tid  = threadIdx.x;
    int lane = tid & 63;
    int wv   = tid >> 6;
    int l16  = lane & 15;
    int lg   = lane >> 4;

    int blk  = blockIdx.x;
    int tblk = blk & 63;
    int bh   = blk >> 6;

    int t0 = tblk * 64 + wv * 16;

    // A-fragments: K rows (t), 8 contiguous d per lane
    const unsigned short* kp = Kt + ((size_t)bh * S_LEN + t0 + l16) * HD + lg * 8;
    bf16x8 kf0 = *(const bf16x8*)kp;
    bf16x8 kf1 = *(const bf16x8*)(kp + 32);

    f32x4 oacc[4];
#pragma unroll
    for (int nt = 0; nt < 4; nt++) { oacc[nt][0]=0.f; oacc[nt][1]=0.f; oacc[nt][2]=0.f; oacc[nt][3]=0.f; }
    float mrow[4] = {-1e30f, -1e30f, -1e30f, -1e30f};
    float lrow[4] = {0.f, 0.f, 0.f, 0.f};

    __shared__ unsigned short Plds[4][16 * 64];
    unsigned short* Pw = Plds[wv];

    const unsigned short* Qbh = Qt + (size_t)bh * S_LEN * HD;
    const unsigned short* Vbh = Vn + ((size_t)bh * 64) * S_LEN;

    const float LOG2E = 1.44269504088896f;

    for (int s0 = 0; s0 < S_LEN; s0 += 64) {
        // ---- S = Kq . Q^T  (16 t x 64 s per wave) ----
        f32x4 sacc[4];
#pragma unroll
        for (int stile = 0; stile < 4; stile++) {
            const unsigned short* qp = Qbh + (size_t)(s0 + stile * 16 + l16) * HD + lg * 8;
            bf16x8 q0 = *(const bf16x8*)qp;
            bf16x8 q1 = *(const bf16x8*)(qp + 32);
            f32x4 c; c[0]=0.f; c[1]=0.f; c[2]=0.f; c[3]=0.f;
            c = __builtin_amdgcn_mfma_f32_16x16x32_bf16(kf0, q0, c, 0, 0, 0);
            c = __builtin_amdgcn_mfma_f32_16x16x32_bf16(kf1, q1, c, 0, 0, 0);
            sacc[stile] = c;
        }
        // log2 domain
#pragma unroll
        for (int stile = 0; stile < 4; stile++)
#pragma unroll
            for (int j = 0; j < 4; j++) sacc[stile][j] *= LOG2E;

        // ---- online softmax over s (wave-parallel, per row j) ----
        float pv[4][4];  // [j][stile]
#pragma unroll
        for (int j = 0; j < 4; j++) {
            float cm = fmaxf(fmaxf(sacc[0][j], sacc[1][j]), fmaxf(sacc[2][j], sacc[3][j]));
#pragma unroll
            for (int off = 1; off < 16; off <<= 1) cm = fmaxf(cm, __shfl_xor(cm, off));
            float newm  = fmaxf(mrow[j], cm);
            float alpha = exp2f(mrow[j] - newm);
            mrow[j] = newm;
            float rs = 0.f;
#pragma unroll
            for (int stile = 0; stile < 4; stile++) {
                float p = exp2f(sacc[stile][j] - newm);
                pv[j][stile] = p;
                rs += p;
            }
#pragma unroll
            for (int off = 1; off < 16; off <<= 1) rs += __shfl_xor(rs, off);
            lrow[j] = lrow[j] * alpha + rs;
            oacc[0][j] *= alpha; oacc[1][j] *= alpha; oacc[2][j] *= alpha; oacc[3][j] *= alpha;
        }

        // ---- P -> LDS (bf16), XOR-swizzled at 8-elem (16B) chunks ----
#pragma unroll
        for (int j = 0; j < 4; j++) {
            int r  = lg * 4 + j;
            int rx = r & 7;
#pragma unroll
            for (int stile = 0; stile < 4; stile++) {
                int ch = (stile * 2 + (l16 >> 3)) ^ rx;
                Pw[r * 64 + ch * 8 + (l16 & 7)] = f2bf(pv[j][stile]);
            }
        }

        // ---- read P A-fragments (row = l16, 8 contiguous s) ----
        int rxr = l16 & 7;
        bf16x8 pa0 = *(const bf16x8*)&Pw[l16 * 64 + ((0 * 4 + lg) ^ rxr) * 8];
        bf16x8 pa1 = *(const bf16x8*)&Pw[l16 * 64 + ((1 * 4 + lg) ^ rxr) * 8];

        // ---- O += P . V  (V natural layout: contiguous along s) ----
#pragma unroll
        for (int nt = 0; nt < 4; nt++) {
            const unsigned short* vp = Vbh + (size_t)(nt * 16 + l16) * S_LEN + s0 + lg * 8;
            bf16x8 v0 = *(const bf16x8*)vp;
            bf16x8 v1 = *(const bf16x8*)(vp + 32);
            oacc[nt] = __builtin_amdgcn_mfma_f32_16x16x32_bf16(pa0, v0, oacc[nt], 0, 0, 0);
            oacc[nt] = __builtin_amdgcn_mfma_f32_16x16x32_bf16(pa1, v1, oacc[nt], 0, 0, 0);
        }
    }

    // ---- normalize, transpose (t-major -> w-major) via LDS, store ----
#pragma unroll
    for (int j = 0; j < 4; j++) {
        float r = 1.0f / lrow[j];
        oacc[0][j] *= r; oacc[1][j] *= r; oacc[2][j] *= r; oacc[3][j] *= r;
    }
    __shared__ float Tl[4][64][17];
#pragma unroll
    for (int nt = 0; nt < 4; nt++)
#pragma unroll
        for (int j = 0; j < 4; j++)
            Tl[wv][nt * 16 + l16][lg * 4 + j] = oacc[nt][j];

    float* op = out + ((size_t)bh * 64 + lane) * S_LEN + t0;
#pragma unroll
    for (int i = 0; i < 16; i++) op[i] = Tl[wv][lane][i];
}

extern "C" void kernel_launch(void* const* d_in, const int* in_sizes, int n_in,
                              void* d_out, int out_size, void* d_ws, size_t ws_size,
                              hipStream_t stream)
{
    const float* X  = (const float*)d_in[0];
    const float* Wq = (const float*)d_in[1];
    const float* bq = (const float*)d_in[2];
    const float* Wk = (const float*)d_in[3];
    const float* bk = (const float*)d_in[4];
    const float* Wv = (const float*)d_in[5];
    const float* bv = (const float*)d_in[6];
    float* out = (float*)d_out;

    const size_t ELEMS = (size_t)16 * S_LEN * HD;  // 4M bf16 per tensor
    unsigned short* Qt = (unsigned short*)d_ws;
    unsigned short* Kt = Qt + ELEMS;
    unsigned short* Vn = Kt + ELEMS;

    dim3 blk(256);
    proj_kernel<<<512, blk, 0, stream>>>(X, Wq, bq, Qt, 1.0f,   1);
    proj_kernel<<<512, blk, 0, stream>>>(X, Wk, bk, Kt, 0.125f, 1);
    proj_kernel<<<512, blk, 0, stream>>>(X, Wv, bv, Vn, 1.0f,   0);
    attn_kernel<<<1024, blk, 0, stream>>>(Qt, Kt, Vn, out);
}

// Round 2
// 536.330 us; speedup vs baseline: 1.3026x; 1.3026x over previous
//
#include <hip/hip_runtime.h>
#include <stdint.h>

// MultiHeadedSelfAttention: B=4, C=256, S=4096, O=256, H=4, D=64
// softmax over axis -2  =>  scores^T is standard flash attn with Qfa=K, Kfa=Q.
// This version: D[s,t] QK orientation (in-lane softmax), MFMA projections with
// split-bf16 (hi+lo) inputs for f32-level accuracy.

#define S_LEN 4096
#define HD 64
#define LOG2E 1.44269504088896f

typedef __attribute__((ext_vector_type(8))) __bf16 bf16x8;
typedef __attribute__((ext_vector_type(8))) unsigned short u16x8;
typedef __attribute__((ext_vector_type(4))) float f32x4;

__device__ __forceinline__ unsigned short f2bf(float f) {
    unsigned int u = __float_as_uint(f);
    u = (u + 0x7FFFu + ((u >> 16) & 1u)) >> 16;
    return (unsigned short)u;
}

__device__ __forceinline__ unsigned int cvt_pk_bf16(float lo, float hi) {
    unsigned int r;
    asm("v_cvt_pk_bf16_f32 %0, %1, %2" : "=v"(r) : "v"(lo), "v"(hi));
    return r;
}

// ---------------- X f32 [B,C,S] -> Xt bf16 hi/lo [B*S, C] ----------------
// grid 1024 = b(4) x sTile(64) x cTile(4); block 256
__global__ __launch_bounds__(256) void cvtX(const float* __restrict__ X,
                                            unsigned short* __restrict__ Xh,
                                            unsigned short* __restrict__ Xl) {
    __shared__ float LT[64][65];
    int tid = threadIdx.x, tx = tid & 63, ty = tid >> 6;
    int id = blockIdx.x;
    int ct = id & 3;
    int st = (id >> 2) & 63;
    int b  = id >> 8;
    const float* Xp = X + ((size_t)b << 20) + ((size_t)(ct * 64 + ty) << 12) + st * 64 + tx;
#pragma unroll
    for (int p = 0; p < 16; p++)
        LT[tx][p * 4 + ty] = Xp[(size_t)(p * 4) << 12];
    __syncthreads();
    int s = tid >> 2, cc = (tid & 3) * 16;
    size_t ob = ((size_t)(b * S_LEN + st * 64 + s)) * 256 + ct * 64 + cc;
#pragma unroll
    for (int h = 0; h < 2; h++) {
        u16x8 vh, vl;
#pragma unroll
        for (int i = 0; i < 8; i++) {
            float x = LT[s][cc + h * 8 + i];
            unsigned short hb = f2bf(x);
            float hf = __uint_as_float((unsigned int)hb << 16);
            vh[i] = hb;
            vl[i] = f2bf(x - hf);
        }
        *(u16x8*)(Xh + ob + h * 8) = vh;
        *(u16x8*)(Xl + ob + h * 8) = vl;
    }
}

// ---------------- W f32 -> bf16 hi/lo. Wb layout [z][2][65536] ----------------
// grid 96 = z(3) x 32; block 256, 8 elems/thread
__global__ __launch_bounds__(256) void cvtW(const float* __restrict__ Wq,
                                            const float* __restrict__ Wk,
                                            const float* __restrict__ Wv,
                                            unsigned short* __restrict__ Wb) {
    int id = blockIdx.x;
    int z = id >> 5, blk = id & 31;
    const float* src = (z == 0) ? Wq : ((z == 1) ? Wk : Wv);
    int base = blk * 2048 + threadIdx.x * 8;
    u16x8 vh, vl;
#pragma unroll
    for (int i = 0; i < 8; i++) {
        float x = src[base + i];
        unsigned short hb = f2bf(x);
        float hf = __uint_as_float((unsigned int)hb << 16);
        vh[i] = hb;
        vl[i] = f2bf(x - hf);
    }
    *(u16x8*)(Wb + (size_t)z * 131072 + base) = vh;
    *(u16x8*)(Wb + (size_t)z * 131072 + 65536 + base) = vl;
}

// ---------------- projection GEMM: D[s,o] = Xt[s,:] . W[o,:]^T + b ----------------
// grid 1536: z = bid/512; r = bid%512: mBlk = r&127 (128 s-rows), oBlk = r>>7 (64 o)
// block 256 = 4 waves: sHalf=(wv&1)*64, oHalf=(wv>>1)*32; wave = 64s x 32o
__global__ __launch_bounds__(256) void proj_gemm(
    const unsigned short* __restrict__ Xh, const unsigned short* __restrict__ Xl,
    const unsigned short* __restrict__ Wb,
    const float* __restrict__ bq, const float* __restrict__ bk, const float* __restrict__ bv,
    unsigned short* __restrict__ Qt, unsigned short* __restrict__ Kt,
    unsigned short* __restrict__ Vn) {
    int tid = threadIdx.x, lane = tid & 63, wv = tid >> 6;
    int l16 = lane & 15, lg = lane >> 4;
    int bid = blockIdx.x;
    int z = bid / 512;
    int r = bid % 512;
    int mBlk = r & 127, oBlk = r >> 7;

    const float* bias = (z == 0) ? bq : ((z == 1) ? bk : bv);
    const unsigned short* Wh = Wb + (size_t)z * 131072;
    const unsigned short* Wl = Wh + 65536;

    int sBase = mBlk * 128 + (wv & 1) * 64;   // global s-row 0..16383
    int oBase = oBlk * 64 + (wv >> 1) * 32;   // 0..255

    f32x4 acc[4][2] = {};

    const unsigned short* Ah_p = Xh + (size_t)(sBase + l16) * 256 + lg * 8;
    const unsigned short* Al_p = Xl + (size_t)(sBase + l16) * 256 + lg * 8;
    const unsigned short* Bh_p = Wh + (size_t)(oBase + l16) * 256 + lg * 8;
    const unsigned short* Bl_p = Wl + (size_t)(oBase + l16) * 256 + lg * 8;

    for (int kk = 0; kk < 8; kk++) {
        int ko = kk * 32;
        bf16x8 ah[4], al[4], bh[2], bl[2];
#pragma unroll
        for (int mt = 0; mt < 4; mt++) {
            ah[mt] = *(const bf16x8*)(Ah_p + mt * 16 * 256 + ko);
            al[mt] = *(const bf16x8*)(Al_p + mt * 16 * 256 + ko);
        }
#pragma unroll
        for (int nt = 0; nt < 2; nt++) {
            bh[nt] = *(const bf16x8*)(Bh_p + nt * 16 * 256 + ko);
            bl[nt] = *(const bf16x8*)(Bl_p + nt * 16 * 256 + ko);
        }
#pragma unroll
        for (int mt = 0; mt < 4; mt++)
#pragma unroll
            for (int nt = 0; nt < 2; nt++) {
                acc[mt][nt] = __builtin_amdgcn_mfma_f32_16x16x32_bf16(ah[mt], bh[nt], acc[mt][nt], 0, 0, 0);
                acc[mt][nt] = __builtin_amdgcn_mfma_f32_16x16x32_bf16(ah[mt], bl[nt], acc[mt][nt], 0, 0, 0);
                acc[mt][nt] = __builtin_amdgcn_mfma_f32_16x16x32_bf16(al[mt], bh[nt], acc[mt][nt], 0, 0, 0);
            }
    }

    float b0 = bias[oBase + l16];
    float b1 = bias[oBase + 16 + l16];
    int b = mBlk >> 5;

    if (z < 2) {
        unsigned short* dst = (z == 0) ? Qt : Kt;
        float sc = (z == 1) ? (0.125f * LOG2E) : 1.0f;
        int head = oBlk;
        int d0 = (wv >> 1) * 32 + l16;
        size_t rowbase = ((size_t)(b * 4 + head)) * S_LEN;
#pragma unroll
        for (int mt = 0; mt < 4; mt++)
#pragma unroll
            for (int j = 0; j < 4; j++) {
                int s = (mBlk & 31) * 128 + (wv & 1) * 64 + mt * 16 + lg * 4 + j;
                size_t off = (rowbase + s) * HD;
                dst[off + d0]      = f2bf((acc[mt][0][j] + b0) * sc);
                dst[off + d0 + 16] = f2bf((acc[mt][1][j] + b1) * sc);
            }
    } else {
        // V: transpose to [B*O][S] via LDS
        __shared__ unsigned short TL[64][136];
        int o0l = (wv >> 1) * 32 + l16;
#pragma unroll
        for (int mt = 0; mt < 4; mt++) {
            int sl = (wv & 1) * 64 + mt * 16 + lg * 4;
            *(unsigned int*)&TL[o0l][sl]          = cvt_pk_bf16(acc[mt][0][0] + b0, acc[mt][0][1] + b0);
            *(unsigned int*)&TL[o0l][sl + 2]      = cvt_pk_bf16(acc[mt][0][2] + b0, acc[mt][0][3] + b0);
            *(unsigned int*)&TL[o0l + 16][sl]     = cvt_pk_bf16(acc[mt][1][0] + b1, acc[mt][1][1] + b1);
            *(unsigned int*)&TL[o0l + 16][sl + 2] = cvt_pk_bf16(acc[mt][1][2] + b1, acc[mt][1][3] + b1);
        }
        __syncthreads();
        int ol = tid >> 2, sc0 = (tid & 3) * 32;
        size_t base = ((size_t)(b * 256 + oBlk * 64 + ol)) * S_LEN + (mBlk & 31) * 128 + sc0;
#pragma unroll
        for (int u = 0; u < 4; u++) {
            u16x8 v = *(u16x8*)&TL[ol][sc0 + u * 8];
            *(u16x8*)(Vn + base + u * 8) = v;
        }
    }
}

// ---------------- flash attention, D[s,t] orientation ----------------
// grid 1024 = bh(16) x tblk(64) (XCD-swizzled); block 256 (4 waves, wave = 16 t)
__global__ __launch_bounds__(256) void attn_v2(const unsigned short* __restrict__ Qt,
                                               const unsigned short* __restrict__ Kt,
                                               const unsigned short* __restrict__ Vn,
                                               float* __restrict__ out) {
    int tid = threadIdx.x, lane = tid & 63, wv = tid >> 6;
    int l16 = lane & 15, lg = lane >> 4;

    int blk = blockIdx.x;
    int swz = (blk & 7) * 128 + (blk >> 3);   // 1024 % 8 == 0: bijective
    int tblk = swz & 63, bh = swz >> 6;
    int t0 = tblk * 64 + wv * 16;

    // K fragments (B-operand: col = t, k = d), held for whole loop
    const unsigned short* kp = Kt + ((size_t)(bh * S_LEN) + t0 + l16) * HD + lg * 8;
    bf16x8 kf0 = *(const bf16x8*)kp;
    bf16x8 kf1 = *(const bf16x8*)(kp + 32);

    const unsigned short* Qbh = Qt + (size_t)bh * S_LEN * HD;
    const unsigned short* Vbh = Vn + (size_t)(bh * 64) * S_LEN;

    f32x4 oacc[4] = {};          // [nt]: d = nt*16 + lg*4 + j, t = l16
    float m = -1e30f, l = 0.f;   // per-lane state for t = t0 + l16

    __shared__ unsigned short Plds[4][16 * 64];
    unsigned short* Pw = Plds[wv];
    int wrow = l16 * 64;
    int rx = l16 & 7;

    // preload Q fragments for iter 0 (A-operand: row = s, k = d)
    bf16x8 qa[4][2];
#pragma unroll
    for (int st = 0; st < 4; st++) {
        const unsigned short* qp = Qbh + (size_t)(st * 16 + l16) * HD + lg * 8;
        qa[st][0] = *(const bf16x8*)qp;
        qa[st][1] = *(const bf16x8*)(qp + 32);
    }

    for (int s0 = 0; s0 < S_LEN; s0 += 64) {
        // ---- S^T tile: D[s_row, t_col], log2-domain (K pre-scaled) ----
        f32x4 sacc[4];
#pragma unroll
        for (int st = 0; st < 4; st++) {
            f32x4 c = {};
            c = __builtin_amdgcn_mfma_f32_16x16x32_bf16(qa[st][0], kf0, c, 0, 0, 0);
            c = __builtin_amdgcn_mfma_f32_16x16x32_bf16(qa[st][1], kf1, c, 0, 0, 0);
            sacc[st] = c;
        }
        // prefetch next-iteration Q
        int sn = (s0 + 64) & (S_LEN - 1);
#pragma unroll
        for (int st = 0; st < 4; st++) {
            const unsigned short* qp = Qbh + (size_t)(sn + st * 16 + l16) * HD + lg * 8;
            qa[st][0] = *(const bf16x8*)qp;
            qa[st][1] = *(const bf16x8*)(qp + 32);
        }
        // prefetch V tile (A-operand: row = d, k = s)
        bf16x8 va[4][2];
#pragma unroll
        for (int nt = 0; nt < 4; nt++) {
            const unsigned short* vp = Vbh + (size_t)(nt * 16 + l16) * S_LEN + s0 + lg * 8;
            va[nt][0] = *(const bf16x8*)vp;
            va[nt][1] = *(const bf16x8*)(vp + 32);
        }

        // ---- online softmax over s: in-lane 16 + xor16/xor32 ----
        float c01 = fmaxf(fmaxf(sacc[0][0], sacc[0][1]), fmaxf(sacc[0][2], sacc[0][3]));
        float c23 = fmaxf(fmaxf(sacc[1][0], sacc[1][1]), fmaxf(sacc[1][2], sacc[1][3]));
        float c45 = fmaxf(fmaxf(sacc[2][0], sacc[2][1]), fmaxf(sacc[2][2], sacc[2][3]));
        float c67 = fmaxf(fmaxf(sacc[3][0], sacc[3][1]), fmaxf(sacc[3][2], sacc[3][3]));
        float cmax = fmaxf(fmaxf(c01, c23), fmaxf(c45, c67));
        cmax = fmaxf(cmax, __shfl_xor(cmax, 16));
        cmax = fmaxf(cmax, __shfl_xor(cmax, 32));

        if (!__all(cmax <= m + 8.0f)) {   // defer-max (T13)
            float newm = fmaxf(m, cmax);
            float al = exp2f(m - newm);
            m = newm;
            l *= al;
#pragma unroll
            for (int nt = 0; nt < 4; nt++) oacc[nt] *= al;
        }

        float rs = 0.f;
#pragma unroll
        for (int st = 0; st < 4; st++)
#pragma unroll
            for (int j = 0; j < 4; j++) {
                sacc[st][j] = exp2f(sacc[st][j] - m);
                rs += sacc[st][j];
            }
        rs += __shfl_xor(rs, 16);
        rs += __shfl_xor(rs, 32);
        l += rs;

        // ---- pack P -> LDS (bf16, chunk-XOR swizzled): P[t][s] ----
#pragma unroll
        for (int st = 0; st < 4; st++) {
            unsigned int w0 = cvt_pk_bf16(sacc[st][0], sacc[st][1]);
            unsigned int w1 = cvt_pk_bf16(sacc[st][2], sacc[st][3]);
            int sl = st * 16 + lg * 4;
            int elem = wrow + (((sl >> 3) ^ rx) << 3) + (sl & 7);
            uint2 w; w.x = w0; w.y = w1;
            *(uint2*)(&Pw[elem]) = w;
        }

        // ---- P B-fragments (col = t = l16, k = s contiguous) ----
        bf16x8 pb0 = *(const bf16x8*)&Pw[wrow + ((lg ^ rx) << 3)];
        bf16x8 pb1 = *(const bf16x8*)&Pw[wrow + (((4 + lg) ^ rx) << 3)];

        // ---- O += V . P : D[d_row, t_col] ----
#pragma unroll
        for (int nt = 0; nt < 4; nt++) {
            oacc[nt] = __builtin_amdgcn_mfma_f32_16x16x32_bf16(va[nt][0], pb0, oacc[nt], 0, 0, 0);
            oacc[nt] = __builtin_amdgcn_mfma_f32_16x16x32_bf16(va[nt][1], pb1, oacc[nt], 0, 0, 0);
        }
    }

    // ---- epilogue: normalize and store (d rows, t cols -> natural out layout) ----
    float rinv = 1.0f / l;
    size_t obase = (size_t)(bh * 64) * S_LEN + t0 + l16;
#pragma unroll
    for (int nt = 0; nt < 4; nt++)
#pragma unroll
        for (int j = 0; j < 4; j++)
            out[obase + (size_t)(nt * 16 + lg * 4 + j) * S_LEN] = oacc[nt][j] * rinv;
}

extern "C" void kernel_launch(void* const* d_in, const int* in_sizes, int n_in,
                              void* d_out, int out_size, void* d_ws, size_t ws_size,
                              hipStream_t stream) {
    const float* X  = (const float*)d_in[0];
    const float* Wq = (const float*)d_in[1];
    const float* bq = (const float*)d_in[2];
    const float* Wk = (const float*)d_in[3];
    const float* bk = (const float*)d_in[4];
    const float* Wv = (const float*)d_in[5];
    const float* bv = (const float*)d_in[6];
    float* out = (float*)d_out;

    const size_t ELEMS = (size_t)16 * S_LEN * HD;  // 4,194,304
    unsigned short* Qt = (unsigned short*)d_ws;
    unsigned short* Kt = Qt + ELEMS;
    unsigned short* Vn = Kt + ELEMS;
    unsigned short* Wb = Vn + ELEMS;               // 3*2*65536 u16

    // Xh/Xl live in d_out (16MB) and are fully consumed before attn overwrites it
    unsigned short* Xh = (unsigned short*)d_out;
    unsigned short* Xl = Xh + (size_t)16384 * 256;

    cvtX<<<1024, 256, 0, stream>>>(X, Xh, Xl);
    cvtW<<<96, 256, 0, stream>>>(Wq, Wk, Wv, Wb);
    proj_gemm<<<1536, 256, 0, stream>>>(Xh, Xl, Wb, bq, bk, bv, Qt, Kt, Vn);
    attn_v2<<<1024, 256, 0, stream>>>(Qt, Kt, Vn, out);
}